// Round 20
// baseline (233.403 us; speedup 1.0000x reference)
//
#include <hip/hip_runtime.h>

static constexpr int F_IN  = 128;
static constexpr int F_H   = 64;
static constexpr int F_OUT = 10;

static constexpr int NPB_SHIFT = 9;            // 512 nodes per coarse bucket
static constexpr int NPB = 1 << NPB_SHIFT;
static constexpr int MAXC = 256;               // max coarse buckets (N <= 131072)
static constexpr int EPB = 4096;               // edges per part1 block (16/thread)

// bf16 helpers
__device__ __forceinline__ unsigned short f2bf(float f) {          // RNE
    unsigned u = __float_as_uint(f);
    return (unsigned short)((u + 0x7fff + ((u >> 16) & 1)) >> 16);
}
__device__ __forceinline__ float bf_lo(unsigned u) { return __uint_as_float(u << 16); }
__device__ __forceinline__ float bf_hi(unsigned u) { return __uint_as_float(u & 0xffff0000u); }

__device__ __forceinline__ int load_idx(const void* ein, bool f64, long i) {
    return f64 ? (int)((const long long*)ein)[i] : ((const int*)ein)[i];
}

// ---------------------------------------------------------------- fused part1 + gemm1 (R19-verified)
__global__ __launch_bounds__(256) void k_pre(const void* __restrict__ ein,
                                             const float* __restrict__ ew,
                                             int* __restrict__ gcur,
                                             unsigned long long* __restrict__ packed,
                                             int E, int NC, int cap, int PB,
                                             const float* __restrict__ x,
                                             const float* __restrict__ W1,
                                             unsigned short* __restrict__ h1b, int M) {
    __shared__ float As[128][16];   // 8 KB (gemm role)
    __shared__ float Ws[16][64];    // 4 KB
    __shared__ int lcnt[MAXC];
    __shared__ int lofs[MAXC];
    __shared__ int sflag;
    int tid = threadIdx.x;
    if ((int)blockIdx.x < PB) {
        // ---------------- part1 body (single-pass, 16 edges/thread) ------
        if (tid < NC) lcnt[tid] = 0;
        if (tid < 64) {
            unsigned long long v = ((const unsigned long long*)ein)[tid];
            int hz = ((v >> 32) == 0ull) ? 1 : 0;
            int all64 = __all(hz);
            if (tid == 0) sflag = all64;
        }
        __syncthreads();
        bool f = sflag != 0;
        int base = blockIdx.x * EPB;
        int   es[16];
        int   ed[16];
        float ww[16];
#pragma unroll
        for (int j = 0; j < 16; ++j) {
            int e = base + j * 256 + tid;
            if (e < E) {
                es[j] = load_idx(ein, f, e);
                ed[j] = load_idx(ein, f, (long)E + e);
                ww[j] = ew[e];
                atomicAdd(&lcnt[ed[j] >> NPB_SHIFT], 1);
            }
        }
        __syncthreads();
        if (tid < NC) {
            int c = lcnt[tid];
            lofs[tid] = c ? atomicAdd(&gcur[tid], c) : 0;
            lcnt[tid] = 0;   // reuse as local cursor
        }
        __syncthreads();
#pragma unroll
        for (int j = 0; j < 16; ++j) {
            int e = base + j * 256 + tid;
            if (e < E) {
                int b = ed[j] >> NPB_SHIFT;
                int pos = lofs[b] + atomicAdd(&lcnt[b], 1);
                if (pos < cap) {
                    unsigned long long u = (unsigned long long)__float_as_uint(ww[j])
                                         | ((unsigned long long)(unsigned)es[j] << 32)
                                         | ((unsigned long long)(unsigned)(ed[j] & (NPB - 1)) << 49);
                    packed[(long)b * cap + pos] = u;
                }
            }
        }
    } else {
        // ---------------- gemm1 body (128x64 tile, BK=16) ----------------
        constexpr int K = F_IN;
        int tx = tid & 15;
        int ty = tid >> 4;
        int rb = ((int)blockIdx.x - PB) * 128;
        float acc[8][4] = {};
        for (int kc = 0; kc < K; kc += 16) {
            __syncthreads();
#pragma unroll
            for (int i = 0; i < 2; ++i) {          // stage A: 512 float4
                int e = tid + i * 256;
                int r = e >> 2, g = e & 3;
                int gr = rb + r;
                float4 v = make_float4(0.f, 0.f, 0.f, 0.f);
                if (gr < M) v = *(const float4*)&x[(long)gr * K + kc + g * 4];
                int gs = g ^ ((r >> 3) & 3);
                *(float4*)&As[r][gs * 4] = v;
            }
            {                                      // stage W: 256 float4
                int k = tid >> 4, n4 = tid & 15;
                *(float4*)&Ws[k][n4 * 4] = *(const float4*)&W1[(long)(kc + k) * 64 + n4 * 4];
            }
            __syncthreads();
#pragma unroll
            for (int g = 0; g < 4; ++g) {
                float4 b0 = *(const float4*)&Ws[g * 4 + 0][tx * 4];
                float4 b1 = *(const float4*)&Ws[g * 4 + 1][tx * 4];
                float4 b2 = *(const float4*)&Ws[g * 4 + 2][tx * 4];
                float4 b3 = *(const float4*)&Ws[g * 4 + 3][tx * 4];
                int gs = (g ^ (ty & 3)) * 4;
#pragma unroll
                for (int rr = 0; rr < 8; ++rr) {
                    float4 a = *(const float4*)&As[ty * 8 + rr][gs];
                    acc[rr][0] = fmaf(a.x, b0.x, acc[rr][0]);
                    acc[rr][1] = fmaf(a.x, b0.y, acc[rr][1]);
                    acc[rr][2] = fmaf(a.x, b0.z, acc[rr][2]);
                    acc[rr][3] = fmaf(a.x, b0.w, acc[rr][3]);
                    acc[rr][0] = fmaf(a.y, b1.x, acc[rr][0]);
                    acc[rr][1] = fmaf(a.y, b1.y, acc[rr][1]);
                    acc[rr][2] = fmaf(a.y, b1.z, acc[rr][2]);
                    acc[rr][3] = fmaf(a.y, b1.w, acc[rr][3]);
                    acc[rr][0] = fmaf(a.z, b2.x, acc[rr][0]);
                    acc[rr][1] = fmaf(a.z, b2.y, acc[rr][1]);
                    acc[rr][2] = fmaf(a.z, b2.z, acc[rr][2]);
                    acc[rr][3] = fmaf(a.z, b2.w, acc[rr][3]);
                    acc[rr][0] = fmaf(a.w, b3.x, acc[rr][0]);
                    acc[rr][1] = fmaf(a.w, b3.y, acc[rr][1]);
                    acc[rr][2] = fmaf(a.w, b3.z, acc[rr][2]);
                    acc[rr][3] = fmaf(a.w, b3.w, acc[rr][3]);
                }
            }
        }
#pragma unroll
        for (int rr = 0; rr < 8; ++rr) {
            int gr = rb + ty * 8 + rr;
            if (gr < M) {
                ushort4 v;
                v.x = f2bf(acc[rr][0]); v.y = f2bf(acc[rr][1]);
                v.z = f2bf(acc[rr][2]); v.w = f2bf(acc[rr][3]);
                *(ushort4*)&h1b[(long)gr * 64 + tx * 4] = v;
            }
        }
    }
}

// ---------------------------------------------------------------- per-bucket hist + padded scan
__global__ __launch_bounds__(256) void k_chist(const unsigned long long* __restrict__ packed,
                                               const int* __restrict__ gcur,
                                               int* __restrict__ rp,
                                               int* __restrict__ pbt,
                                               float* __restrict__ dinv,
                                               int N, int cap) {
    __shared__ int   lc[NPB];
    __shared__ float ld[NPB];
    __shared__ int   sm[256];
    int b = blockIdx.x, tid = threadIdx.x;
#pragma unroll
    for (int i = tid; i < NPB; i += 256) { lc[i] = 0; ld[i] = 0.0f; }
    __syncthreads();
    int cnt = gcur[b];
    const unsigned long long* pk = packed + (long)b * cap;
    for (int p = tid; p < cnt; p += 256) {
        unsigned long long u = pk[p];
        int dl = (int)(u >> 49);
        atomicAdd(&lc[dl], 1);
        atomicAdd(&ld[dl], __uint_as_float((unsigned int)u));
    }
    __syncthreads();
    int c0 = lc[tid * 2], c1 = lc[tid * 2 + 1];
    int pp0 = (c0 + 15) & ~15, pp1 = (c1 + 15) & ~15;  // padded degs (gran 16)
    int s = pp0 + pp1;
    sm[tid] = s;
    __syncthreads();
    for (int off = 1; off < 256; off <<= 1) {
        int v = 0;
        if (tid >= off) v = sm[tid - off];
        __syncthreads();
        sm[tid] += v;
        __syncthreads();
    }
    int excl = sm[tid] - s;                            // local padded exclusive
    int n0 = b << NPB_SHIFT;
    int node0 = n0 + tid * 2, node1 = node0 + 1;
    if (node0 < N) {
        rp[node0]   = excl;
        dinv[node0] = rsqrtf(ld[tid * 2] + 1.0f);
    }
    if (node1 < N) {
        rp[node1]   = excl + pp0;
        dinv[node1] = rsqrtf(ld[tid * 2 + 1] + 1.0f);
    }
    if (tid == 255) pbt[b] = sm[255];                  // bucket padded total
}

// ---------------------------------------------------------------- per-bucket CSR scatter
__global__ __launch_bounds__(256) void k_cscatter(const unsigned long long* __restrict__ packed,
                                                  const int* __restrict__ gcur,
                                                  const int* __restrict__ rp,
                                                  const int* __restrict__ pbt,
                                                  const float* __restrict__ dinv,
                                                  uint2* __restrict__ recs,
                                                  int* __restrict__ rpabs,
                                                  int N, int NC, int cap) {
    __shared__ int   cur[NPB];
    __shared__ float dd[NPB];
    __shared__ int   sm[256];
    int b = blockIdx.x, tid = threadIdx.x;
    int c = (tid < NC) ? pbt[tid] : 0;
    sm[tid] = c;
    __syncthreads();
    for (int off = 1; off < 256; off <<= 1) {
        int v = 0;
        if (tid >= off) v = sm[tid - off];
        __syncthreads();
        sm[tid] += v;
        __syncthreads();
    }
    int pbtb = pbt[b];
    int pb_  = sm[b] - pbtb;                  // exclusive prefix = pbase[b]
    if (b == NC - 1 && tid == 255) rpabs[N] = sm[255];
    int n0 = b << NPB_SHIFT;
#pragma unroll
    for (int i = tid; i < NPB; i += 256) {
        int node = n0 + i;
        int r = (node < N) ? rp[node] + pb_ : 0;
        cur[i] = r;
        dd[i]  = (node < N) ? dinv[node] : 0.0f;
        if (node < N) rpabs[node] = r;
    }
    __syncthreads();
    int cnt = gcur[b];
    const unsigned long long* pk = packed + (long)b * cap;
    for (int p = tid; p < cnt; p += 256) {
        unsigned long long u = pk[p];
        int dl = (int)(u >> 49);
        int s  = (int)((u >> 32) & 0x1FFFF);
        float w = __uint_as_float((unsigned int)u);
        int pos = atomicAdd(&cur[dl], 1);
        uint2 r;
        r.x = (unsigned)(s << 7);             // byte offset into bf16 h
        r.y = __float_as_uint(dinv[s] * w * dd[dl]);
        recs[pos] = r;
    }
    __syncthreads();
    for (int i = tid; i < NPB; i += 256) {    // zero-fill pad gaps
        int node = n0 + i;
        if (node < N) {
            int el = (i == NPB - 1 || node + 1 >= N) ? pbtb : rp[node + 1];
            int end = el + pb_;
            for (int p = cur[i]; p < end; ++p) recs[p] = make_uint2(0u, 0u);
        }
    }
}

// ---------------------------------------------------------------- GEMM v2 (gemm2): bf16 A
template <int K, bool ABF16>
__global__ __launch_bounds__(256) void k_gemm(const void* __restrict__ A,
                                              const float* __restrict__ W,
                                              unsigned short* __restrict__ Cb, int M) {
    __shared__ float As[128][32];   // 16 KB, granule-swizzled
    __shared__ float Ws[32][64];    // 8 KB
    int tid = threadIdx.x;
    int tx = tid & 15;              // col group
    int ty = tid >> 4;              // row group
    int rb = blockIdx.x * 128;
    float acc[8][4] = {};
    for (int kc = 0; kc < K; kc += 32) {
        __syncthreads();
#pragma unroll
        for (int i = 0; i < 4; ++i) {          // stage A
            int e = tid + i * 256;
            int r = e >> 3, g = e & 7;
            int gr = rb + r;
            float4 v = make_float4(0.f, 0.f, 0.f, 0.f);
            if (gr < M) {
                if (ABF16) {
                    uint2 u = *(const uint2*)&((const unsigned short*)A)[(long)gr * K + kc + g * 4];
                    v = make_float4(bf_lo(u.x), bf_hi(u.x), bf_lo(u.y), bf_hi(u.y));
                } else {
                    v = *(const float4*)&((const float*)A)[(long)gr * K + kc + g * 4];
                }
            }
            int gs = g ^ ((r >> 3) & 7);
            *(float4*)&As[r][gs * 4] = v;
        }
#pragma unroll
        for (int i = 0; i < 2; ++i) {          // stage W
            int e = tid + i * 256;
            int k = e >> 4, n4 = e & 15;
            *(float4*)&Ws[k][n4 * 4] = *(const float4*)&W[(long)(kc + k) * 64 + n4 * 4];
        }
        __syncthreads();
#pragma unroll
        for (int g = 0; g < 8; ++g) {
            float4 b0 = *(const float4*)&Ws[g * 4 + 0][tx * 4];
            float4 b1 = *(const float4*)&Ws[g * 4 + 1][tx * 4];
            float4 b2 = *(const float4*)&Ws[g * 4 + 2][tx * 4];
            float4 b3 = *(const float4*)&Ws[g * 4 + 3][tx * 4];
            int gs = (g ^ (ty & 7)) * 4;
#pragma unroll
            for (int rr = 0; rr < 8; ++rr) {
                float4 a = *(const float4*)&As[ty * 8 + rr][gs];
                acc[rr][0] = fmaf(a.x, b0.x, acc[rr][0]);
                acc[rr][1] = fmaf(a.x, b0.y, acc[rr][1]);
                acc[rr][2] = fmaf(a.x, b0.z, acc[rr][2]);
                acc[rr][3] = fmaf(a.x, b0.w, acc[rr][3]);
                acc[rr][0] = fmaf(a.y, b1.x, acc[rr][0]);
                acc[rr][1] = fmaf(a.y, b1.y, acc[rr][1]);
                acc[rr][2] = fmaf(a.y, b1.z, acc[rr][2]);
                acc[rr][3] = fmaf(a.y, b1.w, acc[rr][3]);
                acc[rr][0] = fmaf(a.z, b2.x, acc[rr][0]);
                acc[rr][1] = fmaf(a.z, b2.y, acc[rr][1]);
                acc[rr][2] = fmaf(a.z, b2.z, acc[rr][2]);
                acc[rr][3] = fmaf(a.z, b2.w, acc[rr][3]);
                acc[rr][0] = fmaf(a.w, b3.x, acc[rr][0]);
                acc[rr][1] = fmaf(a.w, b3.y, acc[rr][1]);
                acc[rr][2] = fmaf(a.w, b3.z, acc[rr][2]);
                acc[rr][3] = fmaf(a.w, b3.w, acc[rr][3]);
            }
        }
    }
#pragma unroll
    for (int rr = 0; rr < 8; ++rr) {
        int gr = rb + ty * 8 + rr;
        if (gr < M) {
            ushort4 v;
            v.x = f2bf(acc[rr][0]); v.y = f2bf(acc[rr][1]);
            v.z = f2bf(acc[rr][2]); v.w = f2bf(acc[rr][3]);
            *(ushort4*)&Cb[(long)gr * 64 + tx * 4] = v;
        }
    }
}

// ---------------------------------------------------------------- aggregation v9 (layer 1, R16-verified)
// 16 fg-lanes x 4 es-slots, two 16-rec blocks per iteration. DO NOT TOUCH.
__global__ __launch_bounds__(256, 4) void k_agg(const unsigned short* __restrict__ hb,
                                                const int* __restrict__ rp,
                                                const uint2* __restrict__ recs,
                                                const float* __restrict__ dinv,
                                                const float* __restrict__ bias,
                                                unsigned short* __restrict__ outb, int N) {
    int wid  = (blockIdx.x * 256 + threadIdx.x) >> 6;
    int lane = threadIdx.x & 63;
    int fg   = lane & 15;        // features fg*4 .. fg*4+3
    int es   = lane >> 4;        // edge slot 0..3
    if (wid >= N) return;
    int fg8 = fg * 8;
    const char* hbase = (const char*)hb;
    int p0 = rp[wid], p1 = rp[wid + 1];
    float a0 = 0.f, a1 = 0.f, a2 = 0.f, a3 = 0.f;
    int pb = p0 + es * 4;
    for (; pb + 16 < p1; pb += 32) {           // two 16-blocks per iteration
        uint4 r01 = *(const uint4*)&recs[pb];
        uint4 r23 = *(const uint4*)&recs[pb + 2];
        uint4 r45 = *(const uint4*)&recs[pb + 16];
        uint4 r67 = *(const uint4*)&recs[pb + 18];
        uint2 h0 = *(const uint2*)(hbase + r01.x + fg8);
        uint2 h1 = *(const uint2*)(hbase + r01.z + fg8);
        uint2 h2 = *(const uint2*)(hbase + r23.x + fg8);
        uint2 h3 = *(const uint2*)(hbase + r23.z + fg8);
        uint2 h4 = *(const uint2*)(hbase + r45.x + fg8);
        uint2 h5 = *(const uint2*)(hbase + r45.z + fg8);
        uint2 h6 = *(const uint2*)(hbase + r67.x + fg8);
        uint2 h7 = *(const uint2*)(hbase + r67.z + fg8);
        float w0 = __uint_as_float(r01.y), w1 = __uint_as_float(r01.w);
        float w2 = __uint_as_float(r23.y), w3 = __uint_as_float(r23.w);
        float w4 = __uint_as_float(r45.y), w5 = __uint_as_float(r45.w);
        float w6 = __uint_as_float(r67.y), w7 = __uint_as_float(r67.w);
        a0 = fmaf(w0, bf_lo(h0.x), a0); a1 = fmaf(w0, bf_hi(h0.x), a1);
        a2 = fmaf(w0, bf_lo(h0.y), a2); a3 = fmaf(w0, bf_hi(h0.y), a3);
        a0 = fmaf(w1, bf_lo(h1.x), a0); a1 = fmaf(w1, bf_hi(h1.x), a1);
        a2 = fmaf(w1, bf_lo(h1.y), a2); a3 = fmaf(w1, bf_hi(h1.y), a3);
        a0 = fmaf(w2, bf_lo(h2.x), a0); a1 = fmaf(w2, bf_hi(h2.x), a1);
        a2 = fmaf(w2, bf_lo(h2.y), a2); a3 = fmaf(w2, bf_hi(h2.y), a3);
        a0 = fmaf(w3, bf_lo(h3.x), a0); a1 = fmaf(w3, bf_hi(h3.x), a1);
        a2 = fmaf(w3, bf_lo(h3.y), a2); a3 = fmaf(w3, bf_hi(h3.y), a3);
        a0 = fmaf(w4, bf_lo(h4.x), a0); a1 = fmaf(w4, bf_hi(h4.x), a1);
        a2 = fmaf(w4, bf_lo(h4.y), a2); a3 = fmaf(w4, bf_hi(h4.y), a3);
        a0 = fmaf(w5, bf_lo(h5.x), a0); a1 = fmaf(w5, bf_hi(h5.x), a1);
        a2 = fmaf(w5, bf_lo(h5.y), a2); a3 = fmaf(w5, bf_hi(h5.y), a3);
        a0 = fmaf(w6, bf_lo(h6.x), a0); a1 = fmaf(w6, bf_hi(h6.x), a1);
        a2 = fmaf(w6, bf_lo(h6.y), a2); a3 = fmaf(w6, bf_hi(h6.y), a3);
        a0 = fmaf(w7, bf_lo(h7.x), a0); a1 = fmaf(w7, bf_hi(h7.x), a1);
        a2 = fmaf(w7, bf_lo(h7.y), a2); a3 = fmaf(w7, bf_hi(h7.y), a3);
    }
    if (pb < p1) {                             // tail: one 16-block
        uint4 r01 = *(const uint4*)&recs[pb];
        uint4 r23 = *(const uint4*)&recs[pb + 2];
        uint2 h0 = *(const uint2*)(hbase + r01.x + fg8);
        uint2 h1 = *(const uint2*)(hbase + r01.z + fg8);
        uint2 h2 = *(const uint2*)(hbase + r23.x + fg8);
        uint2 h3 = *(const uint2*)(hbase + r23.z + fg8);
        float w0 = __uint_as_float(r01.y), w1 = __uint_as_float(r01.w);
        float w2 = __uint_as_float(r23.y), w3 = __uint_as_float(r23.w);
        a0 = fmaf(w0, bf_lo(h0.x), a0); a1 = fmaf(w0, bf_hi(h0.x), a1);
        a2 = fmaf(w0, bf_lo(h0.y), a2); a3 = fmaf(w0, bf_hi(h0.y), a3);
        a0 = fmaf(w1, bf_lo(h1.x), a0); a1 = fmaf(w1, bf_hi(h1.x), a1);
        a2 = fmaf(w1, bf_lo(h1.y), a2); a3 = fmaf(w1, bf_hi(h1.y), a3);
        a0 = fmaf(w2, bf_lo(h2.x), a0); a1 = fmaf(w2, bf_hi(h2.x), a1);
        a2 = fmaf(w2, bf_lo(h2.y), a2); a3 = fmaf(w2, bf_hi(h2.y), a3);
        a0 = fmaf(w3, bf_lo(h3.x), a0); a1 = fmaf(w3, bf_hi(h3.x), a1);
        a2 = fmaf(w3, bf_lo(h3.y), a2); a3 = fmaf(w3, bf_hi(h3.y), a3);
    }
#pragma unroll
    for (int m = 16; m <= 32; m <<= 1) {
        a0 += __shfl_xor(a0, m);
        a1 += __shfl_xor(a1, m);
        a2 += __shfl_xor(a2, m);
        a3 += __shfl_xor(a3, m);
    }
    float di  = dinv[wid];
    float di2 = di * di;
    uint2 hs = *(const uint2*)(hbase + ((long)wid << 7) + fg8);
    float4 bv = *(const float4*)&bias[fg * 4];
    a0 = fmaf(bf_lo(hs.x), di2, a0 + bv.x);
    a1 = fmaf(bf_hi(hs.x), di2, a1 + bv.y);
    a2 = fmaf(bf_lo(hs.y), di2, a2 + bv.z);
    a3 = fmaf(bf_hi(hs.y), di2, a3 + bv.w);
    if (es == 0) {
        ushort4 r;
        r.x = f2bf(fmaxf(a0, 0.f));
        r.y = f2bf(fmaxf(a1, 0.f));
        r.z = f2bf(fmaxf(a2, 0.f));
        r.w = f2bf(fmaxf(a3, 0.f));
        *(ushort4*)&outb[(long)wid * 64 + fg * 4] = r;
    }
}

// ---------------------------------------------------------------- aggregation + fused FC (layer 2)
// Separate plain function (NOT a template variant of k_agg — R11 lesson).
// Hot loop verbatim from k_agg; epilogue computes out[wid] = relu(h2) @ Wfc
// + bfc directly (saves the g2b write, the k_fc dispatch, and its 12.8 MB
// re-read). fg-butterfly masks 1/2/4/8 stay within an es-group.
__global__ __launch_bounds__(256, 4) void k_aggf(const unsigned short* __restrict__ hb,
                                                 const int* __restrict__ rp,
                                                 const uint2* __restrict__ recs,
                                                 const float* __restrict__ dinv,
                                                 const float* __restrict__ bias,
                                                 const float* __restrict__ Wfc,
                                                 const float* __restrict__ bfc,
                                                 float* __restrict__ out, int N) {
    int wid  = (blockIdx.x * 256 + threadIdx.x) >> 6;
    int lane = threadIdx.x & 63;
    int fg   = lane & 15;        // features fg*4 .. fg*4+3
    int es   = lane >> 4;        // edge slot 0..3
    if (wid >= N) return;
    int fg8 = fg * 8;
    const char* hbase = (const char*)hb;
    int p0 = rp[wid], p1 = rp[wid + 1];
    float a0 = 0.f, a1 = 0.f, a2 = 0.f, a3 = 0.f;
    int pb = p0 + es * 4;
    for (; pb + 16 < p1; pb += 32) {           // two 16-blocks per iteration
        uint4 r01 = *(const uint4*)&recs[pb];
        uint4 r23 = *(const uint4*)&recs[pb + 2];
        uint4 r45 = *(const uint4*)&recs[pb + 16];
        uint4 r67 = *(const uint4*)&recs[pb + 18];
        uint2 h0 = *(const uint2*)(hbase + r01.x + fg8);
        uint2 h1 = *(const uint2*)(hbase + r01.z + fg8);
        uint2 h2 = *(const uint2*)(hbase + r23.x + fg8);
        uint2 h3 = *(const uint2*)(hbase + r23.z + fg8);
        uint2 h4 = *(const uint2*)(hbase + r45.x + fg8);
        uint2 h5 = *(const uint2*)(hbase + r45.z + fg8);
        uint2 h6 = *(const uint2*)(hbase + r67.x + fg8);
        uint2 h7 = *(const uint2*)(hbase + r67.z + fg8);
        float w0 = __uint_as_float(r01.y), w1 = __uint_as_float(r01.w);
        float w2 = __uint_as_float(r23.y), w3 = __uint_as_float(r23.w);
        float w4 = __uint_as_float(r45.y), w5 = __uint_as_float(r45.w);
        float w6 = __uint_as_float(r67.y), w7 = __uint_as_float(r67.w);
        a0 = fmaf(w0, bf_lo(h0.x), a0); a1 = fmaf(w0, bf_hi(h0.x), a1);
        a2 = fmaf(w0, bf_lo(h0.y), a2); a3 = fmaf(w0, bf_hi(h0.y), a3);
        a0 = fmaf(w1, bf_lo(h1.x), a0); a1 = fmaf(w1, bf_hi(h1.x), a1);
        a2 = fmaf(w1, bf_lo(h1.y), a2); a3 = fmaf(w1, bf_hi(h1.y), a3);
        a0 = fmaf(w2, bf_lo(h2.x), a0); a1 = fmaf(w2, bf_hi(h2.x), a1);
        a2 = fmaf(w2, bf_lo(h2.y), a2); a3 = fmaf(w2, bf_hi(h2.y), a3);
        a0 = fmaf(w3, bf_lo(h3.x), a0); a1 = fmaf(w3, bf_hi(h3.x), a1);
        a2 = fmaf(w3, bf_lo(h3.y), a2); a3 = fmaf(w3, bf_hi(h3.y), a3);
        a0 = fmaf(w4, bf_lo(h4.x), a0); a1 = fmaf(w4, bf_hi(h4.x), a1);
        a2 = fmaf(w4, bf_lo(h4.y), a2); a3 = fmaf(w4, bf_hi(h4.y), a3);
        a0 = fmaf(w5, bf_lo(h5.x), a0); a1 = fmaf(w5, bf_hi(h5.x), a1);
        a2 = fmaf(w5, bf_lo(h5.y), a2); a3 = fmaf(w5, bf_hi(h5.y), a3);
        a0 = fmaf(w6, bf_lo(h6.x), a0); a1 = fmaf(w6, bf_hi(h6.x), a1);
        a2 = fmaf(w6, bf_lo(h6.y), a2); a3 = fmaf(w6, bf_hi(h6.y), a3);
        a0 = fmaf(w7, bf_lo(h7.x), a0); a1 = fmaf(w7, bf_hi(h7.x), a1);
        a2 = fmaf(w7, bf_lo(h7.y), a2); a3 = fmaf(w7, bf_hi(h7.y), a3);
    }
    if (pb < p1) {                             // tail: one 16-block
        uint4 r01 = *(const uint4*)&recs[pb];
        uint4 r23 = *(const uint4*)&recs[pb + 2];
        uint2 h0 = *(const uint2*)(hbase + r01.x + fg8);
        uint2 h1 = *(const uint2*)(hbase + r01.z + fg8);
        uint2 h2 = *(const uint2*)(hbase + r23.x + fg8);
        uint2 h3 = *(const uint2*)(hbase + r23.z + fg8);
        float w0 = __uint_as_float(r01.y), w1 = __uint_as_float(r01.w);
        float w2 = __uint_as_float(r23.y), w3 = __uint_as_float(r23.w);
        a0 = fmaf(w0, bf_lo(h0.x), a0); a1 = fmaf(w0, bf_hi(h0.x), a1);
        a2 = fmaf(w0, bf_lo(h0.y), a2); a3 = fmaf(w0, bf_hi(h0.y), a3);
        a0 = fmaf(w1, bf_lo(h1.x), a0); a1 = fmaf(w1, bf_hi(h1.x), a1);
        a2 = fmaf(w1, bf_lo(h1.y), a2); a3 = fmaf(w1, bf_hi(h1.y), a3);
        a0 = fmaf(w2, bf_lo(h2.x), a0); a1 = fmaf(w2, bf_hi(h2.x), a1);
        a2 = fmaf(w2, bf_lo(h2.y), a2); a3 = fmaf(w2, bf_hi(h2.y), a3);
        a0 = fmaf(w3, bf_lo(h3.x), a0); a1 = fmaf(w3, bf_hi(h3.x), a1);
        a2 = fmaf(w3, bf_lo(h3.y), a2); a3 = fmaf(w3, bf_hi(h3.y), a3);
    }
#pragma unroll
    for (int m = 16; m <= 32; m <<= 1) {
        a0 += __shfl_xor(a0, m);
        a1 += __shfl_xor(a1, m);
        a2 += __shfl_xor(a2, m);
        a3 += __shfl_xor(a3, m);
    }
    float di  = dinv[wid];
    float di2 = di * di;
    uint2 hs = *(const uint2*)(hbase + ((long)wid << 7) + fg8);
    float4 bv = *(const float4*)&bias[fg * 4];
    a0 = fmaf(bf_lo(hs.x), di2, a0 + bv.x);
    a1 = fmaf(bf_hi(hs.x), di2, a1 + bv.y);
    a2 = fmaf(bf_lo(hs.y), di2, a2 + bv.z);
    a3 = fmaf(bf_hi(hs.y), di2, a3 + bv.w);
    float r0 = fmaxf(a0, 0.f), r1 = fmaxf(a1, 0.f);
    float r2 = fmaxf(a2, 0.f), r3 = fmaxf(a3, 0.f);
    // fused FC: p[j] = sum_f relu(h2)[f] * Wfc[f][j] (reduce over 16 fg lanes)
    float p[10];
#pragma unroll
    for (int j = 0; j < 10; ++j) p[j] = 0.f;
    float rr4[4] = {r0, r1, r2, r3};
#pragma unroll
    for (int t = 0; t < 4; ++t) {
        const float* wr = &Wfc[(fg * 4 + t) * 10];
        float2 w01 = *(const float2*)&wr[0];
        float2 w23 = *(const float2*)&wr[2];
        float2 w45 = *(const float2*)&wr[4];
        float2 w67 = *(const float2*)&wr[6];
        float2 w89 = *(const float2*)&wr[8];
        p[0] = fmaf(rr4[t], w01.x, p[0]); p[1] = fmaf(rr4[t], w01.y, p[1]);
        p[2] = fmaf(rr4[t], w23.x, p[2]); p[3] = fmaf(rr4[t], w23.y, p[3]);
        p[4] = fmaf(rr4[t], w45.x, p[4]); p[5] = fmaf(rr4[t], w45.y, p[5]);
        p[6] = fmaf(rr4[t], w67.x, p[6]); p[7] = fmaf(rr4[t], w67.y, p[7]);
        p[8] = fmaf(rr4[t], w89.x, p[8]); p[9] = fmaf(rr4[t], w89.y, p[9]);
    }
#pragma unroll
    for (int j = 0; j < 10; ++j) {
        p[j] += __shfl_xor(p[j], 1);
        p[j] += __shfl_xor(p[j], 2);
        p[j] += __shfl_xor(p[j], 4);
        p[j] += __shfl_xor(p[j], 8);
    }
    if (lane == 0) {
        *(float2*)&out[(long)wid * 10 + 0] = make_float2(p[0] + bfc[0], p[1] + bfc[1]);
        *(float2*)&out[(long)wid * 10 + 2] = make_float2(p[2] + bfc[2], p[3] + bfc[3]);
        *(float2*)&out[(long)wid * 10 + 4] = make_float2(p[4] + bfc[4], p[5] + bfc[5]);
        *(float2*)&out[(long)wid * 10 + 6] = make_float2(p[6] + bfc[6], p[7] + bfc[7]);
        *(float2*)&out[(long)wid * 10 + 8] = make_float2(p[8] + bfc[8], p[9] + bfc[9]);
    }
}

// ---------------------------------------------------------------- launch
extern "C" void kernel_launch(void* const* d_in, const int* in_sizes, int n_in,
                              void* d_out, int out_size, void* d_ws, size_t ws_size,
                              hipStream_t stream) {
    const float* x    = (const float*)d_in[0];
    const void*  eidx = d_in[1];
    const float* ew   = (const float*)d_in[2];
    const float* W1   = (const float*)d_in[3];
    const float* b1   = (const float*)d_in[4];
    const float* W2   = (const float*)d_in[5];
    const float* b2   = (const float*)d_in[6];
    const float* Wfc  = (const float*)d_in[7];
    const float* bfc  = (const float*)d_in[8];
    float* out = (float*)d_out;

    const int N  = in_sizes[0] / F_IN;            // 100000
    const int E  = in_sizes[2];                   // 1600000
    const int NC = (N + NPB - 1) >> NPB_SHIFT;    // 196 coarse buckets
    const int cap = E / NC + E / (8 * NC) + 1024; // mean + slack

    char* w = (char*)d_ws;
    size_t off = 0;
    auto alloc = [&](size_t bytes) {
        void* p = w + off;
        off += (bytes + 255) & ~(size_t)255;
        return p;
    };
    float* dinv  = (float*)alloc((size_t)N * 4);
    int*   rp    = (int*)alloc((size_t)(N + 1) * 4);   // bucket-local padded scan
    int*   rpabs = (int*)alloc((size_t)(N + 1) * 4);   // absolute (for agg)
    int*   gcur  = (int*)alloc((size_t)MAXC * 4);
    int*   pbt   = (int*)alloc((size_t)MAXC * 4);
    unsigned long long* packed =
        (unsigned long long*)alloc((size_t)NC * cap * 8);
    uint2* recs  = (uint2*)alloc(((size_t)E + 15u * (size_t)N + 64) * 8);
    unsigned short* h1b = (unsigned short*)alloc((size_t)N * F_H * 2);
    unsigned short* g1b = (unsigned short*)alloc((size_t)N * F_H * 2);
    unsigned short* h2b = h1b;   // alias: h1b dead after agg1
    (void)ws_size;

    hipMemsetAsync(gcur, 0, (size_t)NC * 4, stream);

    const int PB = (E + EPB - 1) / EPB;   // part1 blocks (391)
    const int GB = (N + 127) / 128;       // gemm row-tiles (782)

    k_pre<<<PB + GB, 256, 0, stream>>>(eidx, ew, gcur, packed, E, NC, cap, PB,
                                       x, W1, h1b, N);
    k_chist<<<NC, 256, 0, stream>>>(packed, gcur, rp, pbt, dinv, N, cap);
    k_cscatter<<<NC, 256, 0, stream>>>(packed, gcur, rp, pbt, dinv, recs,
                                       rpabs, N, NC, cap);

    k_agg<<<(N + 3) / 4, 256, 0, stream>>>(h1b, rpabs, recs, dinv, b1, g1b, N);
    k_gemm<F_H, true><<<GB, 256, 0, stream>>>(g1b, W2, h2b, N);          // h2 = bf16(g1@W2)
    k_aggf<<<(N + 3) / 4, 256, 0, stream>>>(h2b, rpabs, recs, dinv, b2,
                                            Wfc, bfc, out, N);
}

// Round 21
// 187.116 us; speedup vs baseline: 1.2474x; 1.2474x over previous
//
#include <hip/hip_runtime.h>

static constexpr int F_IN  = 128;
static constexpr int F_H   = 64;
static constexpr int F_OUT = 10;

static constexpr int NPB_SHIFT = 9;            // 512 nodes per coarse bucket
static constexpr int NPB = 1 << NPB_SHIFT;
static constexpr int MAXC = 256;               // max coarse buckets (N <= 131072)
static constexpr int EPB = 4096;               // edges per part1 block (16/thread)

// bf16 helpers
__device__ __forceinline__ unsigned short f2bf(float f) {          // RNE
    unsigned u = __float_as_uint(f);
    return (unsigned short)((u + 0x7fff + ((u >> 16) & 1)) >> 16);
}
__device__ __forceinline__ float bf_lo(unsigned u) { return __uint_as_float(u << 16); }
__device__ __forceinline__ float bf_hi(unsigned u) { return __uint_as_float(u & 0xffff0000u); }

__device__ __forceinline__ int load_idx(const void* ein, bool f64, long i) {
    return f64 ? (int)((const long long*)ein)[i] : ((const int*)ein)[i];
}

// ---------------------------------------------------------------- fused part1 + gemm1 (R19-verified)
__global__ __launch_bounds__(256) void k_pre(const void* __restrict__ ein,
                                             const float* __restrict__ ew,
                                             int* __restrict__ gcur,
                                             unsigned long long* __restrict__ packed,
                                             int E, int NC, int cap, int PB,
                                             const float* __restrict__ x,
                                             const float* __restrict__ W1,
                                             unsigned short* __restrict__ h1b, int M) {
    __shared__ float As[128][16];   // 8 KB (gemm role)
    __shared__ float Ws[16][64];    // 4 KB
    __shared__ int lcnt[MAXC];
    __shared__ int lofs[MAXC];
    __shared__ int sflag;
    int tid = threadIdx.x;
    if ((int)blockIdx.x < PB) {
        // ---------------- part1 body (single-pass, 16 edges/thread) ------
        if (tid < NC) lcnt[tid] = 0;
        if (tid < 64) {
            unsigned long long v = ((const unsigned long long*)ein)[tid];
            int hz = ((v >> 32) == 0ull) ? 1 : 0;
            int all64 = __all(hz);
            if (tid == 0) sflag = all64;
        }
        __syncthreads();
        bool f = sflag != 0;
        int base = blockIdx.x * EPB;
        int   es[16];
        int   ed[16];
        float ww[16];
#pragma unroll
        for (int j = 0; j < 16; ++j) {
            int e = base + j * 256 + tid;
            if (e < E) {
                es[j] = load_idx(ein, f, e);
                ed[j] = load_idx(ein, f, (long)E + e);
                ww[j] = ew[e];
                atomicAdd(&lcnt[ed[j] >> NPB_SHIFT], 1);
            }
        }
        __syncthreads();
        if (tid < NC) {
            int c = lcnt[tid];
            lofs[tid] = c ? atomicAdd(&gcur[tid], c) : 0;
            lcnt[tid] = 0;   // reuse as local cursor
        }
        __syncthreads();
#pragma unroll
        for (int j = 0; j < 16; ++j) {
            int e = base + j * 256 + tid;
            if (e < E) {
                int b = ed[j] >> NPB_SHIFT;
                int pos = lofs[b] + atomicAdd(&lcnt[b], 1);
                if (pos < cap) {
                    unsigned long long u = (unsigned long long)__float_as_uint(ww[j])
                                         | ((unsigned long long)(unsigned)es[j] << 32)
                                         | ((unsigned long long)(unsigned)(ed[j] & (NPB - 1)) << 49);
                    packed[(long)b * cap + pos] = u;
                }
            }
        }
    } else {
        // ---------------- gemm1 body (128x64 tile, BK=16) ----------------
        constexpr int K = F_IN;
        int tx = tid & 15;
        int ty = tid >> 4;
        int rb = ((int)blockIdx.x - PB) * 128;
        float acc[8][4] = {};
        for (int kc = 0; kc < K; kc += 16) {
            __syncthreads();
#pragma unroll
            for (int i = 0; i < 2; ++i) {          // stage A: 512 float4
                int e = tid + i * 256;
                int r = e >> 2, g = e & 3;
                int gr = rb + r;
                float4 v = make_float4(0.f, 0.f, 0.f, 0.f);
                if (gr < M) v = *(const float4*)&x[(long)gr * K + kc + g * 4];
                int gs = g ^ ((r >> 3) & 3);
                *(float4*)&As[r][gs * 4] = v;
            }
            {                                      // stage W: 256 float4
                int k = tid >> 4, n4 = tid & 15;
                *(float4*)&Ws[k][n4 * 4] = *(const float4*)&W1[(long)(kc + k) * 64 + n4 * 4];
            }
            __syncthreads();
#pragma unroll
            for (int g = 0; g < 4; ++g) {
                float4 b0 = *(const float4*)&Ws[g * 4 + 0][tx * 4];
                float4 b1 = *(const float4*)&Ws[g * 4 + 1][tx * 4];
                float4 b2 = *(const float4*)&Ws[g * 4 + 2][tx * 4];
                float4 b3 = *(const float4*)&Ws[g * 4 + 3][tx * 4];
                int gs = (g ^ (ty & 3)) * 4;
#pragma unroll
                for (int rr = 0; rr < 8; ++rr) {
                    float4 a = *(const float4*)&As[ty * 8 + rr][gs];
                    acc[rr][0] = fmaf(a.x, b0.x, acc[rr][0]);
                    acc[rr][1] = fmaf(a.x, b0.y, acc[rr][1]);
                    acc[rr][2] = fmaf(a.x, b0.z, acc[rr][2]);
                    acc[rr][3] = fmaf(a.x, b0.w, acc[rr][3]);
                    acc[rr][0] = fmaf(a.y, b1.x, acc[rr][0]);
                    acc[rr][1] = fmaf(a.y, b1.y, acc[rr][1]);
                    acc[rr][2] = fmaf(a.y, b1.z, acc[rr][2]);
                    acc[rr][3] = fmaf(a.y, b1.w, acc[rr][3]);
                    acc[rr][0] = fmaf(a.z, b2.x, acc[rr][0]);
                    acc[rr][1] = fmaf(a.z, b2.y, acc[rr][1]);
                    acc[rr][2] = fmaf(a.z, b2.z, acc[rr][2]);
                    acc[rr][3] = fmaf(a.z, b2.w, acc[rr][3]);
                    acc[rr][0] = fmaf(a.w, b3.x, acc[rr][0]);
                    acc[rr][1] = fmaf(a.w, b3.y, acc[rr][1]);
                    acc[rr][2] = fmaf(a.w, b3.z, acc[rr][2]);
                    acc[rr][3] = fmaf(a.w, b3.w, acc[rr][3]);
                }
            }
        }
#pragma unroll
        for (int rr = 0; rr < 8; ++rr) {
            int gr = rb + ty * 8 + rr;
            if (gr < M) {
                ushort4 v;
                v.x = f2bf(acc[rr][0]); v.y = f2bf(acc[rr][1]);
                v.z = f2bf(acc[rr][2]); v.w = f2bf(acc[rr][3]);
                *(ushort4*)&h1b[(long)gr * 64 + tx * 4] = v;
            }
        }
    }
}

// ---------------------------------------------------------------- per-bucket hist + padded scan
__global__ __launch_bounds__(256) void k_chist(const unsigned long long* __restrict__ packed,
                                               const int* __restrict__ gcur,
                                               int* __restrict__ rp,
                                               int* __restrict__ pbt,
                                               float* __restrict__ dinv,
                                               int N, int cap) {
    __shared__ int   lc[NPB];
    __shared__ float ld[NPB];
    __shared__ int   sm[256];
    int b = blockIdx.x, tid = threadIdx.x;
#pragma unroll
    for (int i = tid; i < NPB; i += 256) { lc[i] = 0; ld[i] = 0.0f; }
    __syncthreads();
    int cnt = gcur[b];
    const unsigned long long* pk = packed + (long)b * cap;
    for (int p = tid; p < cnt; p += 256) {
        unsigned long long u = pk[p];
        int dl = (int)(u >> 49);
        atomicAdd(&lc[dl], 1);
        atomicAdd(&ld[dl], __uint_as_float((unsigned int)u));
    }
    __syncthreads();
    int c0 = lc[tid * 2], c1 = lc[tid * 2 + 1];
    int pp0 = (c0 + 15) & ~15, pp1 = (c1 + 15) & ~15;  // padded degs (gran 16)
    int s = pp0 + pp1;
    sm[tid] = s;
    __syncthreads();
    for (int off = 1; off < 256; off <<= 1) {
        int v = 0;
        if (tid >= off) v = sm[tid - off];
        __syncthreads();
        sm[tid] += v;
        __syncthreads();
    }
    int excl = sm[tid] - s;                            // local padded exclusive
    int n0 = b << NPB_SHIFT;
    int node0 = n0 + tid * 2, node1 = node0 + 1;
    if (node0 < N) {
        rp[node0]   = excl;
        dinv[node0] = rsqrtf(ld[tid * 2] + 1.0f);
    }
    if (node1 < N) {
        rp[node1]   = excl + pp0;
        dinv[node1] = rsqrtf(ld[tid * 2 + 1] + 1.0f);
    }
    if (tid == 255) pbt[b] = sm[255];                  // bucket padded total
}

// ---------------------------------------------------------------- per-bucket CSR scatter
__global__ __launch_bounds__(256) void k_cscatter(const unsigned long long* __restrict__ packed,
                                                  const int* __restrict__ gcur,
                                                  const int* __restrict__ rp,
                                                  const int* __restrict__ pbt,
                                                  const float* __restrict__ dinv,
                                                  uint2* __restrict__ recs,
                                                  int* __restrict__ rpabs,
                                                  int N, int NC, int cap) {
    __shared__ int   cur[NPB];
    __shared__ float dd[NPB];
    __shared__ int   sm[256];
    int b = blockIdx.x, tid = threadIdx.x;
    int c = (tid < NC) ? pbt[tid] : 0;
    sm[tid] = c;
    __syncthreads();
    for (int off = 1; off < 256; off <<= 1) {
        int v = 0;
        if (tid >= off) v = sm[tid - off];
        __syncthreads();
        sm[tid] += v;
        __syncthreads();
    }
    int pbtb = pbt[b];
    int pb_  = sm[b] - pbtb;                  // exclusive prefix = pbase[b]
    if (b == NC - 1 && tid == 255) rpabs[N] = sm[255];
    int n0 = b << NPB_SHIFT;
#pragma unroll
    for (int i = tid; i < NPB; i += 256) {
        int node = n0 + i;
        int r = (node < N) ? rp[node] + pb_ : 0;
        cur[i] = r;
        dd[i]  = (node < N) ? dinv[node] : 0.0f;
        if (node < N) rpabs[node] = r;
    }
    __syncthreads();
    int cnt = gcur[b];
    const unsigned long long* pk = packed + (long)b * cap;
    for (int p = tid; p < cnt; p += 256) {
        unsigned long long u = pk[p];
        int dl = (int)(u >> 49);
        int s  = (int)((u >> 32) & 0x1FFFF);
        float w = __uint_as_float((unsigned int)u);
        int pos = atomicAdd(&cur[dl], 1);
        uint2 r;
        r.x = (unsigned)(s << 7);             // byte offset into bf16 h
        r.y = __float_as_uint(dinv[s] * w * dd[dl]);
        recs[pos] = r;
    }
    __syncthreads();
    for (int i = tid; i < NPB; i += 256) {    // zero-fill pad gaps
        int node = n0 + i;
        if (node < N) {
            int el = (i == NPB - 1 || node + 1 >= N) ? pbtb : rp[node + 1];
            int end = el + pb_;
            for (int p = cur[i]; p < end; ++p) recs[p] = make_uint2(0u, 0u);
        }
    }
}

// ---------------------------------------------------------------- GEMM v2 (gemm2): bf16 A
template <int K, bool ABF16>
__global__ __launch_bounds__(256) void k_gemm(const void* __restrict__ A,
                                              const float* __restrict__ W,
                                              unsigned short* __restrict__ Cb, int M) {
    __shared__ float As[128][32];   // 16 KB, granule-swizzled
    __shared__ float Ws[32][64];    // 8 KB
    int tid = threadIdx.x;
    int tx = tid & 15;              // col group
    int ty = tid >> 4;              // row group
    int rb = blockIdx.x * 128;
    float acc[8][4] = {};
    for (int kc = 0; kc < K; kc += 32) {
        __syncthreads();
#pragma unroll
        for (int i = 0; i < 4; ++i) {          // stage A
            int e = tid + i * 256;
            int r = e >> 3, g = e & 7;
            int gr = rb + r;
            float4 v = make_float4(0.f, 0.f, 0.f, 0.f);
            if (gr < M) {
                if (ABF16) {
                    uint2 u = *(const uint2*)&((const unsigned short*)A)[(long)gr * K + kc + g * 4];
                    v = make_float4(bf_lo(u.x), bf_hi(u.x), bf_lo(u.y), bf_hi(u.y));
                } else {
                    v = *(const float4*)&((const float*)A)[(long)gr * K + kc + g * 4];
                }
            }
            int gs = g ^ ((r >> 3) & 7);
            *(float4*)&As[r][gs * 4] = v;
        }
#pragma unroll
        for (int i = 0; i < 2; ++i) {          // stage W
            int e = tid + i * 256;
            int k = e >> 4, n4 = e & 15;
            *(float4*)&Ws[k][n4 * 4] = *(const float4*)&W[(long)(kc + k) * 64 + n4 * 4];
        }
        __syncthreads();
#pragma unroll
        for (int g = 0; g < 8; ++g) {
            float4 b0 = *(const float4*)&Ws[g * 4 + 0][tx * 4];
            float4 b1 = *(const float4*)&Ws[g * 4 + 1][tx * 4];
            float4 b2 = *(const float4*)&Ws[g * 4 + 2][tx * 4];
            float4 b3 = *(const float4*)&Ws[g * 4 + 3][tx * 4];
            int gs = (g ^ (ty & 7)) * 4;
#pragma unroll
            for (int rr = 0; rr < 8; ++rr) {
                float4 a = *(const float4*)&As[ty * 8 + rr][gs];
                acc[rr][0] = fmaf(a.x, b0.x, acc[rr][0]);
                acc[rr][1] = fmaf(a.x, b0.y, acc[rr][1]);
                acc[rr][2] = fmaf(a.x, b0.z, acc[rr][2]);
                acc[rr][3] = fmaf(a.x, b0.w, acc[rr][3]);
                acc[rr][0] = fmaf(a.y, b1.x, acc[rr][0]);
                acc[rr][1] = fmaf(a.y, b1.y, acc[rr][1]);
                acc[rr][2] = fmaf(a.y, b1.z, acc[rr][2]);
                acc[rr][3] = fmaf(a.y, b1.w, acc[rr][3]);
                acc[rr][0] = fmaf(a.z, b2.x, acc[rr][0]);
                acc[rr][1] = fmaf(a.z, b2.y, acc[rr][1]);
                acc[rr][2] = fmaf(a.z, b2.z, acc[rr][2]);
                acc[rr][3] = fmaf(a.z, b2.w, acc[rr][3]);
                acc[rr][0] = fmaf(a.w, b3.x, acc[rr][0]);
                acc[rr][1] = fmaf(a.w, b3.y, acc[rr][1]);
                acc[rr][2] = fmaf(a.w, b3.z, acc[rr][2]);
                acc[rr][3] = fmaf(a.w, b3.w, acc[rr][3]);
            }
        }
    }
#pragma unroll
    for (int rr = 0; rr < 8; ++rr) {
        int gr = rb + ty * 8 + rr;
        if (gr < M) {
            ushort4 v;
            v.x = f2bf(acc[rr][0]); v.y = f2bf(acc[rr][1]);
            v.z = f2bf(acc[rr][2]); v.w = f2bf(acc[rr][3]);
            *(ushort4*)&Cb[(long)gr * 64 + tx * 4] = v;
        }
    }
}

// ---------------------------------------------------------------- aggregation v9 (R16-verified)
// 16 fg-lanes x 4 es-slots, two 16-rec blocks per iteration (12 loads in
// flight), plain for-loop + single-block tail. ZERO epilogue additions —
// any extra live state (R11/R20 FC fusion) serializes the gather pipeline.
__global__ __launch_bounds__(256, 4) void k_agg(const unsigned short* __restrict__ hb,
                                                const int* __restrict__ rp,
                                                const uint2* __restrict__ recs,
                                                const float* __restrict__ dinv,
                                                const float* __restrict__ bias,
                                                unsigned short* __restrict__ outb, int N) {
    int wid  = (blockIdx.x * 256 + threadIdx.x) >> 6;
    int lane = threadIdx.x & 63;
    int fg   = lane & 15;        // features fg*4 .. fg*4+3
    int es   = lane >> 4;        // edge slot 0..3
    if (wid >= N) return;
    int fg8 = fg * 8;
    const char* hbase = (const char*)hb;
    int p0 = rp[wid], p1 = rp[wid + 1];
    float a0 = 0.f, a1 = 0.f, a2 = 0.f, a3 = 0.f;
    int pb = p0 + es * 4;
    for (; pb + 16 < p1; pb += 32) {           // two 16-blocks per iteration
        uint4 r01 = *(const uint4*)&recs[pb];
        uint4 r23 = *(const uint4*)&recs[pb + 2];
        uint4 r45 = *(const uint4*)&recs[pb + 16];
        uint4 r67 = *(const uint4*)&recs[pb + 18];
        uint2 h0 = *(const uint2*)(hbase + r01.x + fg8);
        uint2 h1 = *(const uint2*)(hbase + r01.z + fg8);
        uint2 h2 = *(const uint2*)(hbase + r23.x + fg8);
        uint2 h3 = *(const uint2*)(hbase + r23.z + fg8);
        uint2 h4 = *(const uint2*)(hbase + r45.x + fg8);
        uint2 h5 = *(const uint2*)(hbase + r45.z + fg8);
        uint2 h6 = *(const uint2*)(hbase + r67.x + fg8);
        uint2 h7 = *(const uint2*)(hbase + r67.z + fg8);
        float w0 = __uint_as_float(r01.y), w1 = __uint_as_float(r01.w);
        float w2 = __uint_as_float(r23.y), w3 = __uint_as_float(r23.w);
        float w4 = __uint_as_float(r45.y), w5 = __uint_as_float(r45.w);
        float w6 = __uint_as_float(r67.y), w7 = __uint_as_float(r67.w);
        a0 = fmaf(w0, bf_lo(h0.x), a0); a1 = fmaf(w0, bf_hi(h0.x), a1);
        a2 = fmaf(w0, bf_lo(h0.y), a2); a3 = fmaf(w0, bf_hi(h0.y), a3);
        a0 = fmaf(w1, bf_lo(h1.x), a0); a1 = fmaf(w1, bf_hi(h1.x), a1);
        a2 = fmaf(w1, bf_lo(h1.y), a2); a3 = fmaf(w1, bf_hi(h1.y), a3);
        a0 = fmaf(w2, bf_lo(h2.x), a0); a1 = fmaf(w2, bf_hi(h2.x), a1);
        a2 = fmaf(w2, bf_lo(h2.y), a2); a3 = fmaf(w2, bf_hi(h2.y), a3);
        a0 = fmaf(w3, bf_lo(h3.x), a0); a1 = fmaf(w3, bf_hi(h3.x), a1);
        a2 = fmaf(w3, bf_lo(h3.y), a2); a3 = fmaf(w3, bf_hi(h3.y), a3);
        a0 = fmaf(w4, bf_lo(h4.x), a0); a1 = fmaf(w4, bf_hi(h4.x), a1);
        a2 = fmaf(w4, bf_lo(h4.y), a2); a3 = fmaf(w4, bf_hi(h4.y), a3);
        a0 = fmaf(w5, bf_lo(h5.x), a0); a1 = fmaf(w5, bf_hi(h5.x), a1);
        a2 = fmaf(w5, bf_lo(h5.y), a2); a3 = fmaf(w5, bf_hi(h5.y), a3);
        a0 = fmaf(w6, bf_lo(h6.x), a0); a1 = fmaf(w6, bf_hi(h6.x), a1);
        a2 = fmaf(w6, bf_lo(h6.y), a2); a3 = fmaf(w6, bf_hi(h6.y), a3);
        a0 = fmaf(w7, bf_lo(h7.x), a0); a1 = fmaf(w7, bf_hi(h7.x), a1);
        a2 = fmaf(w7, bf_lo(h7.y), a2); a3 = fmaf(w7, bf_hi(h7.y), a3);
    }
    if (pb < p1) {                             // tail: one 16-block
        uint4 r01 = *(const uint4*)&recs[pb];
        uint4 r23 = *(const uint4*)&recs[pb + 2];
        uint2 h0 = *(const uint2*)(hbase + r01.x + fg8);
        uint2 h1 = *(const uint2*)(hbase + r01.z + fg8);
        uint2 h2 = *(const uint2*)(hbase + r23.x + fg8);
        uint2 h3 = *(const uint2*)(hbase + r23.z + fg8);
        float w0 = __uint_as_float(r01.y), w1 = __uint_as_float(r01.w);
        float w2 = __uint_as_float(r23.y), w3 = __uint_as_float(r23.w);
        a0 = fmaf(w0, bf_lo(h0.x), a0); a1 = fmaf(w0, bf_hi(h0.x), a1);
        a2 = fmaf(w0, bf_lo(h0.y), a2); a3 = fmaf(w0, bf_hi(h0.y), a3);
        a0 = fmaf(w1, bf_lo(h1.x), a0); a1 = fmaf(w1, bf_hi(h1.x), a1);
        a2 = fmaf(w1, bf_lo(h1.y), a2); a3 = fmaf(w1, bf_hi(h1.y), a3);
        a0 = fmaf(w2, bf_lo(h2.x), a0); a1 = fmaf(w2, bf_hi(h2.x), a1);
        a2 = fmaf(w2, bf_lo(h2.y), a2); a3 = fmaf(w2, bf_hi(h2.y), a3);
        a0 = fmaf(w3, bf_lo(h3.x), a0); a1 = fmaf(w3, bf_hi(h3.x), a1);
        a2 = fmaf(w3, bf_lo(h3.y), a2); a3 = fmaf(w3, bf_hi(h3.y), a3);
    }
#pragma unroll
    for (int m = 16; m <= 32; m <<= 1) {
        a0 += __shfl_xor(a0, m);
        a1 += __shfl_xor(a1, m);
        a2 += __shfl_xor(a2, m);
        a3 += __shfl_xor(a3, m);
    }
    float di  = dinv[wid];
    float di2 = di * di;
    uint2 hs = *(const uint2*)(hbase + ((long)wid << 7) + fg8);
    float4 bv = *(const float4*)&bias[fg * 4];
    a0 = fmaf(bf_lo(hs.x), di2, a0 + bv.x);
    a1 = fmaf(bf_hi(hs.x), di2, a1 + bv.y);
    a2 = fmaf(bf_lo(hs.y), di2, a2 + bv.z);
    a3 = fmaf(bf_hi(hs.y), di2, a3 + bv.w);
    if (es == 0) {
        ushort4 r;
        r.x = f2bf(fmaxf(a0, 0.f));
        r.y = f2bf(fmaxf(a1, 0.f));
        r.z = f2bf(fmaxf(a2, 0.f));
        r.w = f2bf(fmaxf(a3, 0.f));
        *(ushort4*)&outb[(long)wid * 64 + fg * 4] = r;
    }
}

// ---------------------------------------------------------------- FC: bf16[M,64]@[64,10]+b
__global__ __launch_bounds__(256) void k_fc(const unsigned short* __restrict__ hb,
                                            const float* __restrict__ W,
                                            const float* __restrict__ b,
                                            float* __restrict__ out, int N) {
    __shared__ float Ws[64 * 10];
    __shared__ float bs[16];
    int tid = threadIdx.x;
    for (int e = tid; e < 64 * 10; e += 256) Ws[e] = W[e];
    if (tid < 10) bs[tid] = b[tid];
    __syncthreads();
    int i = blockIdx.x * 256 + tid;
    if (i >= N) return;
    float acc[10];
#pragma unroll
    for (int j = 0; j < 10; ++j) acc[j] = bs[j];
    const uint2* row = (const uint2*)&hb[(long)i * 64];
#pragma unroll
    for (int c = 0; c < 16; ++c) {
        uint2 u = row[c];
        float ax = bf_lo(u.x), ay = bf_hi(u.x);
        float az = bf_lo(u.y), aw = bf_hi(u.y);
#pragma unroll
        for (int j = 0; j < 10; ++j) {
            acc[j] = fmaf(ax, Ws[(4 * c + 0) * 10 + j], acc[j]);
            acc[j] = fmaf(ay, Ws[(4 * c + 1) * 10 + j], acc[j]);
            acc[j] = fmaf(az, Ws[(4 * c + 2) * 10 + j], acc[j]);
            acc[j] = fmaf(aw, Ws[(4 * c + 3) * 10 + j], acc[j]);
        }
    }
#pragma unroll
    for (int j = 0; j < 10; ++j) out[(long)i * 10 + j] = acc[j];
}

// ---------------------------------------------------------------- launch
extern "C" void kernel_launch(void* const* d_in, const int* in_sizes, int n_in,
                              void* d_out, int out_size, void* d_ws, size_t ws_size,
                              hipStream_t stream) {
    const float* x    = (const float*)d_in[0];
    const void*  eidx = d_in[1];
    const float* ew   = (const float*)d_in[2];
    const float* W1   = (const float*)d_in[3];
    const float* b1   = (const float*)d_in[4];
    const float* W2   = (const float*)d_in[5];
    const float* b2   = (const float*)d_in[6];
    const float* Wfc  = (const float*)d_in[7];
    const float* bfc  = (const float*)d_in[8];
    float* out = (float*)d_out;

    const int N  = in_sizes[0] / F_IN;            // 100000
    const int E  = in_sizes[2];                   // 1600000
    const int NC = (N + NPB - 1) >> NPB_SHIFT;    // 196 coarse buckets
    const int cap = E / NC + E / (8 * NC) + 1024; // mean + slack

    char* w = (char*)d_ws;
    size_t off = 0;
    auto alloc = [&](size_t bytes) {
        void* p = w + off;
        off += (bytes + 255) & ~(size_t)255;
        return p;
    };
    float* dinv  = (float*)alloc((size_t)N * 4);
    int*   rp    = (int*)alloc((size_t)(N + 1) * 4);   // bucket-local padded scan
    int*   rpabs = (int*)alloc((size_t)(N + 1) * 4);   // absolute (for agg)
    int*   gcur  = (int*)alloc((size_t)MAXC * 4);
    int*   pbt   = (int*)alloc((size_t)MAXC * 4);
    unsigned long long* packed =
        (unsigned long long*)alloc((size_t)NC * cap * 8);
    uint2* recs  = (uint2*)alloc(((size_t)E + 15u * (size_t)N + 64) * 8);
    unsigned short* h1b = (unsigned short*)alloc((size_t)N * F_H * 2);
    unsigned short* g1b = (unsigned short*)alloc((size_t)N * F_H * 2);
    unsigned short* h2b = h1b;   // alias: h1b dead after agg1
    unsigned short* g2b = g1b;   // alias: g1b dead after gemm2
    (void)ws_size;

    hipMemsetAsync(gcur, 0, (size_t)NC * 4, stream);

    const int PB = (E + EPB - 1) / EPB;   // part1 blocks (391)
    const int GB = (N + 127) / 128;       // gemm row-tiles (782)

    k_pre<<<PB + GB, 256, 0, stream>>>(eidx, ew, gcur, packed, E, NC, cap, PB,
                                       x, W1, h1b, N);
    k_chist<<<NC, 256, 0, stream>>>(packed, gcur, rp, pbt, dinv, N, cap);
    k_cscatter<<<NC, 256, 0, stream>>>(packed, gcur, rp, pbt, dinv, recs,
                                       rpabs, N, NC, cap);

    k_agg<<<(N + 3) / 4, 256, 0, stream>>>(h1b, rpabs, recs, dinv, b1, g1b, N);
    k_gemm<F_H, true><<<GB, 256, 0, stream>>>(g1b, W2, h2b, N);          // h2 = bf16(g1@W2)
    k_agg<<<(N + 3) / 4, 256, 0, stream>>>(h2b, rpabs, recs, dinv, b2, g2b, N);
    k_fc<<<(N + 255) / 256, 256, 0, stream>>>(g2b, Wfc, bfc, out, N);
}